// Round 11
// baseline (882.274 us; speedup 1.0000x reference)
//
#include <hip/hip_runtime.h>
#include <math.h>

#define NB 32
#define CIN 2048
#define HH 14
#define WW 14
#define HW 196
#define DD 128
#define KK 32
#define NCLASS 1000
#define PWN 10
#define NP 100
#define NPIX 25
#define KD 4096
#define BN_EPS 1e-5f
#define YELEMS (NB * HW * DD)    // 802816
#define MTOT (NB * HW)           // 6272 flattened pixels
#define MT 64                    // M-tile (98 tiles, exact)
#define KS 16                    // K-step channels

// ---------------------------------------------------------------------------
// Kernel 0: transpose conv_w [D][CIN] -> w_t [CIN][D] (one-time, ~1 MB).
// ---------------------------------------------------------------------------
__global__ __launch_bounds__(256) void k_wt(const float* __restrict__ cw,
                                            float* __restrict__ wt) {
  __shared__ float T[32][33];
  const int tx = threadIdx.x & 31;
  const int ty = threadIdx.x >> 5;
  const int c0 = blockIdx.x * 32;
  const int d0 = blockIdx.y * 32;
  #pragma unroll
  for (int k = 0; k < 4; ++k)
    T[ty + 8 * k][tx] = cw[(size_t)(d0 + ty + 8 * k) * CIN + c0 + tx];
  __syncthreads();
  #pragma unroll
  for (int k = 0; k < 4; ++k)
    wt[(size_t)(c0 + ty + 8 * k) * DD + d0 + tx] = T[tx][ty + 8 * k];
}

// ---------------------------------------------------------------------------
// Kernel 1: 1x1 conv, LDS-staged double-buffered fp32 GEMM.
// Round-8 PMC fix: VGPR 184 -> ~75 (4p x 8d tile, acc=32 VGPR), MT=64 ->
// 1568 blocks (6.1/CU), LDS 25.6KB (6 blk/CU), __launch_bounds__(256,4).
// Per c-iter/wave: X read is 16-lane broadcast (~free), W 2xb128 2-way alias;
// ~4.5 LDS-cyc vs 64 VALU-cyc -> VALU-bound by 3x even at 16 waves/CU.
// ---------------------------------------------------------------------------
__global__ __launch_bounds__(256, 4) void k_conv(const float* __restrict__ x,
                                                 const float* __restrict__ wt,
                                                 float* __restrict__ y_part,
                                                 int cspl) {
  __shared__ float Xs[2][KS][68];    // 16c x 64m, pad 68
  __shared__ float Ws[2][KS][132];   // 16c x 128d, pad 132

  const int t = threadIdx.x;
  const int m0 = blockIdx.x * MT;
  const int s = blockIdx.y;
  const int c0 = s * cspl;
  const int nsteps = cspl / KS;

  // staging geometry: sr = channel row, one X-f4 + two W-f4 per thread/step
  const int sr = t >> 4;             // 0..15
  const int sq = t & 15;
  const int scx = sq * 4;            // X col (m offset within tile)
  const int scw = sq * 8;            // W col (d offset)
  const int mx = m0 + scx;           // 4-aligned; HW%4==0 -> no b straddle
  const int bx = mx / HW, hx = mx - bx * HW;
  const float* xp = x + (size_t)bx * CIN * HW + (size_t)(c0 + sr) * HW + hx;
  const float* wp = wt + (size_t)(c0 + sr) * DD + scw;

  // compute geometry: 4p x 8d (two d-halves)
  const int pg = t >> 4;             // 0..15
  const int dg = t & 15;             // 0..15
  const int pa = pg * 4;
  const int da = dg * 4;

  float4 acc[2][4];                  // [d-half][p-row], components = d
  #pragma unroll
  for (int di = 0; di < 2; ++di)
    #pragma unroll
    for (int i = 0; i < 4; ++i)
      acc[di][i] = make_float4(0.f, 0.f, 0.f, 0.f);

  // prologue: stage step 0 into buf 0
  {
    float4 xv  = *(const float4*)xp;
    float4 wv1 = *(const float4*)wp;
    float4 wv2 = *(const float4*)(wp + 4);
    *(float4*)&Xs[0][sr][scx]     = xv;
    *(float4*)&Ws[0][sr][scw]     = wv1;
    *(float4*)&Ws[0][sr][scw + 4] = wv2;
  }
  __syncthreads();

  for (int ks = 0; ks < nsteps; ++ks) {
    const int cur = ks & 1;
    float4 xv, wv1, wv2;
    const bool more = (ks + 1 < nsteps);
    if (more) {                      // T14: issue next-step loads EARLY
      const size_t coff = (size_t)(ks + 1) * KS * HW;
      const size_t woff = (size_t)(ks + 1) * KS * DD;
      xv  = *(const float4*)(xp + coff);
      wv1 = *(const float4*)(wp + woff);
      wv2 = *(const float4*)(wp + woff + 4);
    }
    // compute: 16c x 32 FMA/thread
    #pragma unroll
    for (int c = 0; c < KS; ++c) {
      float4 xa = *(const float4*)&Xs[cur][c][pa];
      float4 wa = *(const float4*)&Ws[cur][c][da];
      float4 wb = *(const float4*)&Ws[cur][c][da + 64];
      float xs[4] = {xa.x, xa.y, xa.z, xa.w};
      #pragma unroll
      for (int i = 0; i < 4; ++i) {
        acc[0][i].x += xs[i] * wa.x; acc[0][i].y += xs[i] * wa.y;
        acc[0][i].z += xs[i] * wa.z; acc[0][i].w += xs[i] * wa.w;
        acc[1][i].x += xs[i] * wb.x; acc[1][i].y += xs[i] * wb.y;
        acc[1][i].z += xs[i] * wb.z; acc[1][i].w += xs[i] * wb.w;
      }
    }
    if (more) {                      // loads landed during compute window
      const int nxt = cur ^ 1;
      *(float4*)&Xs[nxt][sr][scx]     = xv;
      *(float4*)&Ws[nxt][sr][scw]     = wv1;
      *(float4*)&Ws[nxt][sr][scw + 4] = wv2;
    }
    __syncthreads();
  }

  // epilogue: coalesced f4 stores (wave = 4 p-rows x full 128-d rows)
  float* yp = y_part + (size_t)s * YELEMS + (size_t)(m0 + pa) * DD;
  #pragma unroll
  for (int i = 0; i < 4; ++i) {
    *(float4*)(yp + (size_t)i * DD + da)      = acc[0][i];
    *(float4*)(yp + (size_t)i * DD + da + 64) = acc[1][i];
  }
}

// ---------------------------------------------------------------------------
// Kernel 2: reduce ksplit partials + conv bias + BN(eval) + ReLU -> y.
// ---------------------------------------------------------------------------
__global__ __launch_bounds__(256) void k_bnred(const float* __restrict__ y_part,
    float* __restrict__ y, const float* __restrict__ convb,
    const float* __restrict__ gamma, const float* __restrict__ beta,
    const float* __restrict__ mean, const float* __restrict__ var,
    int nsplit) {
  int idx = blockIdx.x * 256 + threadIdx.x;
  float4 a = *(const float4*)&y_part[(size_t)idx * 4];
  for (int s = 1; s < nsplit; ++s) {
    float4 p = *(const float4*)&y_part[(size_t)s * YELEMS + (size_t)idx * 4];
    a.x += p.x; a.y += p.y; a.z += p.z; a.w += p.w;
  }
  int d4 = (idx * 4) & (DD - 1);
  float o[4] = {a.x, a.y, a.z, a.w};
  #pragma unroll
  for (int j = 0; j < 4; ++j) {
    int d = d4 + j;
    float inv = gamma[d] * rsqrtf(var[d] + BN_EPS);
    float val = (o[j] + convb[d] - mean[d]) * inv + beta[d];
    o[j] = fmaxf(val, 0.f);
  }
  *(float4*)&y[(size_t)idx * 4] = make_float4(o[0], o[1], o[2], o[3]);
}

// ---------------------------------------------------------------------------
// Kernel 3: soft-VQ encode. Grid (npart, NB); register-accumulated partials,
// plain stores (no global atomics). (unchanged)
// ---------------------------------------------------------------------------
__global__ __launch_bounds__(256) void k_encode(const float* __restrict__ y,
    const float* __restrict__ codewords, const float* __restrict__ scale,
    float* __restrict__ vpart, int ppb) {
  __shared__ float Xs[NPIX][132];
  __shared__ float cws[KK][132];
  __shared__ float cwT[DD][36];
  __shared__ float Am[NPIX][36];
  __shared__ float x2s[NPIX];
  __shared__ float sks[KK];
  __shared__ float c2s[KK];
  __shared__ float scs[KK];
  __shared__ float red[5];

  const int t = threadIdx.x;
  const int part = blockIdx.x;
  const int b = blockIdx.y;
  const int wave = t >> 6, lane = t & 63;

  #pragma unroll
  for (int i = 0; i < 4; ++i) {
    int idx = t + 256 * i;
    int k = idx >> 5;
    int d4 = (idx & 31) * 4;
    *(float4*)&cws[k][d4] = *(const float4*)&codewords[k * DD + d4];
  }
  __syncthreads();
  #pragma unroll
  for (int i = 0; i < 4; ++i) {
    int idx = t + 256 * i;
    int k = idx & 31;
    int d4 = (idx >> 5) * 4;
    float4 vc = *(const float4*)&cws[k][d4];
    cwT[d4 + 0][k] = vc.x; cwT[d4 + 1][k] = vc.y;
    cwT[d4 + 2][k] = vc.z; cwT[d4 + 3][k] = vc.w;
  }
  if (t < KK) {
    float s = 0.f;
    #pragma unroll 8
    for (int d4 = 0; d4 < DD; d4 += 4) {
      float4 c4 = *(const float4*)&cws[t][d4];
      s += c4.x * c4.x + c4.y * c4.y + c4.z * c4.z + c4.w * c4.w;
    }
    c2s[t] = s;
    scs[t] = scale[t];
  }

  const int dd = (t & 63) * 2;
  const int k06 = (t >> 6) * 8;
  float vacc[8][2];
  #pragma unroll
  for (int kk = 0; kk < 8; ++kk) { vacc[kk][0] = 0.f; vacc[kk][1] = 0.f; }

  for (int pp = 0; pp < ppb; ++pp) {
    const int p = part * ppb + pp;
    if (p >= NP) break;
    const int pi = p / PWN, pj = p - pi * PWN;

    __syncthreads();
    #pragma unroll
    for (int i = 0; i < 4; ++i) {
      int idx = t + 256 * i;
      if (idx < NPIX * 32) {
        int n = idx >> 5;
        int d4 = (idx & 31) * 4;
        int di = n / 5, dj = n - di * 5;
        int hw = (pi + di) * WW + (pj + dj);
        *(float4*)&Xs[n][d4] =
            *(const float4*)&y[((size_t)b * HW + hw) * DD + d4];
      }
    }
    __syncthreads();

    for (int n = wave; n < NPIX; n += 4) {
      float a = Xs[n][lane];
      float c = Xs[n][lane + 64];
      float r = a * a + c * c;
      #pragma unroll
      for (int off = 32; off; off >>= 1) r += __shfl_xor(r, off, 64);
      if (lane == 0) x2s[n] = r;
    }
    __syncthreads();

    {
      const int n = t >> 3;
      const int k0 = (t & 7) * 4;
      if (n < NPIX) {
        float a0 = 0.f, a1 = 0.f, a2 = 0.f, a3 = 0.f;
        #pragma unroll 8
        for (int d4 = 0; d4 < DD; d4 += 4) {
          float4 xv = *(const float4*)&Xs[n][d4];
          float4 c0 = *(const float4*)&cwT[d4 + 0][k0];
          float4 c1 = *(const float4*)&cwT[d4 + 1][k0];
          float4 c2 = *(const float4*)&cwT[d4 + 2][k0];
          float4 c3 = *(const float4*)&cwT[d4 + 3][k0];
          a0 += xv.x * c0.x + xv.y * c1.x + xv.z * c2.x + xv.w * c3.x;
          a1 += xv.x * c0.y + xv.y * c1.y + xv.z * c2.y + xv.w * c3.y;
          a2 += xv.x * c0.z + xv.y * c1.z + xv.z * c2.z + xv.w * c3.z;
          a3 += xv.x * c0.w + xv.y * c1.w + xv.z * c2.w + xv.w * c3.w;
        }
        float x2 = x2s[n];
        float l0 = scs[k0 + 0] * (x2 - 2.f * a0 + c2s[k0 + 0]);
        float l1 = scs[k0 + 1] * (x2 - 2.f * a1 + c2s[k0 + 1]);
        float l2 = scs[k0 + 2] * (x2 - 2.f * a2 + c2s[k0 + 2]);
        float l3 = scs[k0 + 3] * (x2 - 2.f * a3 + c2s[k0 + 3]);
        float m = fmaxf(fmaxf(l0, l1), fmaxf(l2, l3));
        m = fmaxf(m, __shfl_xor(m, 1));
        m = fmaxf(m, __shfl_xor(m, 2));
        m = fmaxf(m, __shfl_xor(m, 4));
        float e0 = __expf(l0 - m), e1 = __expf(l1 - m);
        float e2 = __expf(l2 - m), e3 = __expf(l3 - m);
        float s = e0 + e1 + e2 + e3;
        s += __shfl_xor(s, 1);
        s += __shfl_xor(s, 2);
        s += __shfl_xor(s, 4);
        float inv = 1.f / s;
        *(float4*)&Am[n][k0] =
            make_float4(e0 * inv, e1 * inv, e2 * inv, e3 * inv);
      }
    }
    __syncthreads();

    if (t < KK) {
      float s = 0.f;
      #pragma unroll
      for (int n = 0; n < NPIX; ++n) s += Am[n][t];
      sks[t] = s;
    }
    __syncthreads();

    float ea[8][2];
    #pragma unroll
    for (int kk = 0; kk < 8; ++kk) { ea[kk][0] = 0.f; ea[kk][1] = 0.f; }
    #pragma unroll 5
    for (int n = 0; n < NPIX; ++n) {
      float2 xv = *(const float2*)&Xs[n][dd];
      float4 q0 = *(const float4*)&Am[n][k06];
      float4 q1 = *(const float4*)&Am[n][k06 + 4];
      float av[8] = {q0.x, q0.y, q0.z, q0.w, q1.x, q1.y, q1.z, q1.w};
      #pragma unroll
      for (int kk = 0; kk < 8; ++kk) {
        ea[kk][0] += av[kk] * xv.x;
        ea[kk][1] += av[kk] * xv.y;
      }
    }
    float ss = 0.f;
    #pragma unroll
    for (int kk = 0; kk < 8; ++kk) {
      int k = k06 + kk;
      float s = sks[k];
      float2 cv = *(const float2*)&cws[k][dd];
      ea[kk][0] -= s * cv.x;
      ea[kk][1] -= s * cv.y;
      ss += ea[kk][0] * ea[kk][0] + ea[kk][1] * ea[kk][1];
    }
    #pragma unroll
    for (int off = 32; off; off >>= 1) ss += __shfl_xor(ss, off, 64);
    if (lane == 0) red[wave] = ss;
    __syncthreads();
    if (t == 0) {
      float tot = red[0] + red[1] + red[2] + red[3];
      red[4] = 1.f / fmaxf(sqrtf(tot), 1e-12f);
    }
    __syncthreads();
    float rn = red[4];
    #pragma unroll
    for (int kk = 0; kk < 8; ++kk) {
      vacc[kk][0] += ea[kk][0] * rn;
      vacc[kk][1] += ea[kk][1] * rn;
    }
  }

  float* vp = vpart + ((size_t)part * NB + b) * KD;
  #pragma unroll
  for (int kk = 0; kk < 8; ++kk)
    *(float2*)&vp[(k06 + kk) * DD + dd] =
        make_float2(vacc[kk][0], vacc[kk][1]);
}

// ---------------------------------------------------------------------------
// Kernel 3b: v[b][kd] = sum_part vpart[part][b][kd].
// ---------------------------------------------------------------------------
__global__ __launch_bounds__(256) void k_vred(const float* __restrict__ vpart,
                                              float* __restrict__ v,
                                              int npart) {
  int idx = blockIdx.x * 256 + threadIdx.x;
  float4 a = make_float4(0.f, 0.f, 0.f, 0.f);
  for (int pt = 0; pt < npart; ++pt) {
    float4 p = *(const float4*)&vpart[(size_t)pt * NB * KD + (size_t)idx * 4];
    a.x += p.x; a.y += p.y; a.z += p.z; a.w += p.w;
  }
  *(float4*)&v[(size_t)idx * 4] = a;
}

// ---------------------------------------------------------------------------
// Kernel 4: classifier out[32,1000] = v @ cls_w^T + cls_b. (unchanged)
// ---------------------------------------------------------------------------
__global__ __launch_bounds__(256) void k_cls(const float* __restrict__ v,
    const float* __restrict__ cls_w, const float* __restrict__ cls_b,
    float* __restrict__ out) {
  const int wave = threadIdx.x >> 6;
  const int lane = threadIdx.x & 63;
  const int n0 = blockIdx.x * 8 + wave * 2;
  const float* w0 = cls_w + (size_t)n0 * KD;
  const float* w1 = cls_w + (size_t)(n0 + 1) * KD;
  float acc0[NB], acc1[NB];
  #pragma unroll
  for (int b = 0; b < NB; ++b) { acc0[b] = 0.f; acc1[b] = 0.f; }
  #pragma unroll 2
  for (int i = 0; i < 16; ++i) {
    int kd = i * 256 + lane * 4;
    float4 a4 = *(const float4*)&w0[kd];
    float4 b4 = *(const float4*)&w1[kd];
    #pragma unroll
    for (int b = 0; b < NB; ++b) {
      float4 v4 = *(const float4*)&v[b * KD + kd];
      acc0[b] += a4.x * v4.x + a4.y * v4.y + a4.z * v4.z + a4.w * v4.w;
      acc1[b] += b4.x * v4.x + b4.y * v4.y + b4.z * v4.z + b4.w * v4.w;
    }
  }
  #pragma unroll
  for (int b = 0; b < NB; ++b) {
    float r0 = acc0[b], r1 = acc1[b];
    #pragma unroll
    for (int off = 32; off; off >>= 1) {
      r0 += __shfl_xor(r0, off, 64);
      r1 += __shfl_xor(r1, off, 64);
    }
    if (lane == 0) {
      out[b * NCLASS + n0]     = r0 + cls_b[n0];
      out[b * NCLASS + n0 + 1] = r1 + cls_b[n0 + 1];
    }
  }
}

// ---------------------------------------------------------------------------
extern "C" void kernel_launch(void* const* d_in, const int* in_sizes, int n_in,
                              void* d_out, int out_size, void* d_ws, size_t ws_size,
                              hipStream_t stream) {
  const float* x         = (const float*)d_in[0];
  const float* conv_w    = (const float*)d_in[1];
  const float* conv_b    = (const float*)d_in[2];
  const float* bn_gamma  = (const float*)d_in[3];
  const float* bn_beta   = (const float*)d_in[4];
  const float* bn_mean   = (const float*)d_in[5];
  const float* bn_var    = (const float*)d_in[6];
  const float* codewords = (const float*)d_in[7];
  const float* scale     = (const float*)d_in[8];
  const float* cls_w     = (const float*)d_in[9];
  const float* cls_b     = (const float*)d_in[10];
  float* out = (float*)d_out;

  auto need = [](int kspl, int npart) -> size_t {
    size_t scratch = (size_t)kspl * YELEMS;
    size_t vp = (size_t)npart * NB * KD;
    if (vp > scratch) scratch = vp;
    return ((size_t)CIN * DD + scratch + (size_t)YELEMS
            + (size_t)NB * KD) * sizeof(float);
  };
  int ksplit, npart;
  if      (ws_size >= need(16, 25)) { ksplit = 16; npart = 25; }
  else if (ws_size >= need(8, 25))  { ksplit = 8;  npart = 25; }
  else if (ws_size >= need(4, 25))  { ksplit = 4;  npart = 25; }
  else                              { ksplit = 2;  npart = 10; }
  const int cspl = CIN / ksplit;
  const int ppb = (NP + npart - 1) / npart;
  size_t scratchf = (size_t)ksplit * YELEMS;
  if ((size_t)npart * NB * KD > scratchf) scratchf = (size_t)npart * NB * KD;

  float* wt      = (float*)d_ws;
  float* scratch = wt + (size_t)CIN * DD;     // y_part, then vpart
  float* y       = scratch + scratchf;
  float* v       = y + (size_t)YELEMS;

  k_wt<<<dim3(CIN / 32, DD / 32), 256, 0, stream>>>(conv_w, wt);
  k_conv<<<dim3(MTOT / MT, ksplit), 256, 0, stream>>>(x, wt, scratch, cspl);
  k_bnred<<<YELEMS / (256 * 4), 256, 0, stream>>>(
      scratch, y, conv_b, bn_gamma, bn_beta, bn_mean, bn_var, ksplit);
  k_encode<<<dim3(npart, NB), 256, 0, stream>>>(y, codewords, scale,
                                                scratch, ppb);
  k_vred<<<NB * KD / (256 * 4), 256, 0, stream>>>(scratch, v, npart);
  k_cls<<<NCLASS / 8, 256, 0, stream>>>(v, cls_w, cls_b, out);
}